// Round 10
// baseline (505.556 us; speedup 1.0000x reference)
//
#include <hip/hip_runtime.h>

constexpr int N   = 100000;   // nodes
constexpr int E   = 1600000;  // message edges
constexpr int EP  = 200000;   // pos scored edges
constexpr int ES  = 400000;   // total scored edges (pos+neg)
constexpr int CAP = 64;       // per-node fan-in clamp for lane-gather (Poisson(16): P(deg>64)~1e-18)
constexpr int XG2 = 128;      // radix groups (CSR counting-sort fill)
constexpr int DR2 = (N + XG2 - 1) / XG2;    // 782 nodes per group
constexpr int SEGCAP = 14336; // per-group segment capacity (E/128=12500 mean, +16 sigma)
constexpr int EPB = 8192;     // edges per partition block
constexpr int PBS = 1024;     // partition block size
constexpr int NPB = (E + EPB - 1) / EPB;    // 196 partition blocks
constexpr int BSTR = 264;     // gemm1 LDS B k-stride (f16): 264*2B=528B -> bank (4n+4q)%32, 2-way max

typedef _Float16 f16x8 __attribute__((ext_vector_type(8)));
typedef _Float16 f16x4 __attribute__((ext_vector_type(4)));
typedef _Float16 f16x2 __attribute__((ext_vector_type(2)));
typedef float    f32x4 __attribute__((ext_vector_type(4)));

// ---------------------------------------------------------------- Pass A: partition edges
// 196 blocks x 8192 edges, LDS histogram + ONE global atomic per group per
// block. 128 groups; pack = rel(10b)<<17 | src(17b).
__global__ __launch_bounds__(1024) void partition_edges(const int* __restrict__ ei,
                                                        int* __restrict__ gcnt,
                                                        unsigned* __restrict__ eb) {
    __shared__ int lh[XG2];   // block histogram
    __shared__ int rk[XG2];   // running rank counters (init = global base)
    const int tid = threadIdx.x;
    const int e0  = blockIdx.x * EPB;
    if (tid < XG2) lh[tid] = 0;
    __syncthreads();
#pragma unroll
    for (int i = 0; i < EPB; i += PBS) {
        const int e = e0 + i + tid;
        if (e < E) {
            const int d = ei[E + e];
            atomicAdd(&lh[d / DR2], 1);
        }
    }
    __syncthreads();
    if (tid < XG2) rk[tid] = atomicAdd(&gcnt[tid], lh[tid]);  // one hot atomic per group per block
    __syncthreads();
#pragma unroll
    for (int i = 0; i < EPB; i += PBS) {
        const int e = e0 + i + tid;
        if (e < E) {
            const int s   = ei[e];
            const int d   = ei[E + e];
            const int g   = d / DR2;
            const int rel = d - g * DR2;               // < 782 < 2^10
            const int p   = atomicAdd(&rk[g], 1);
            if (p < SEGCAP)
                eb[(size_t)g * SEGCAP + p] = ((unsigned)rel << 17) | (unsigned)s;
        }
    }
}

// ---------------------------------------------------------------- Pass B: CSR counting sort
// 4B scattered col stores cannot be L2-merged (rounds 16/18); one 1024-thread
// block per group finishes the sort in LDS, writes everything coalesced.
// Also emits dinv[n] = rsqrt(deg+1).
__global__ __launch_bounds__(1024) void fill_csr(const unsigned* __restrict__ eb,
                                                 const int* __restrict__ gcnt,
                                                 int* __restrict__ cnt,
                                                 int* __restrict__ rp,
                                                 float* __restrict__ dinv,
                                                 int* __restrict__ colc) {
    __shared__ int hcnt[1024];          // counts -> cursors (DR2=782 used)
    __shared__ int wsum[16];
    __shared__ unsigned stage[SEGCAP];  // 57.3 KB
    const int g   = blockIdx.x;
    const int tid = threadIdx.x;
    const int cg  = min(gcnt[g], SEGCAP);
    const unsigned* seg = eb + (size_t)g * SEGCAP;

    hcnt[tid] = 0;
    __syncthreads();
    for (int i = tid; i < cg; i += 1024)
        atomicAdd(&hcnt[seg[i] >> 17], 1);
    __syncthreads();

    // exclusive scan over 1024 counters (wave scan + wave-sum scan)
    const int c    = hcnt[tid];
    const int lane = tid & 63;
    const int wid  = tid >> 6;
    int incl = c;
#pragma unroll
    for (int off = 1; off < 64; off <<= 1) {
        const int v = __shfl_up(incl, off);
        if (lane >= off) incl += v;
    }
    if (lane == 63) wsum[wid] = incl;
    __syncthreads();
    if (tid < 16) {
        int v = wsum[tid];
#pragma unroll
        for (int off = 1; off < 16; off <<= 1) {
            const int u = __shfl_up(v, off);
            if (tid >= off) v += u;
        }
        wsum[tid] = v;   // inclusive wave sums
    }
    __syncthreads();
    const int excl = incl - c + (wid ? wsum[wid - 1] : 0);

    const int base = g * DR2;
    if (tid < DR2 && base + tid < N) {
        cnt [base + tid] = c;                      // full in-degree
        rp  [base + tid] = g * SEGCAP + excl;      // CSR row start
        dinv[base + tid] = rsqrtf((float)c + 1.0f);
    }
    __syncthreads();       // scan reads done before cursor overwrite
    hcnt[tid] = excl;
    __syncthreads();

    for (int i = tid; i < cg; i += 1024) {
        const unsigned pk = seg[i];
        const int p = atomicAdd(&hcnt[pk >> 17], 1);
        stage[p] = pk & 0x1FFFFu;
    }
    __syncthreads();
    for (int i = tid; i < cg; i += 1024)
        colc[(size_t)g * SEGCAP + i] = (int)stage[i];   // full-line streaming writes
}

// ---------------------------------------------------------------- W1 transpose prep
__global__ __launch_bounds__(256) void w1_transpose(const float* __restrict__ W1,
                                                    _Float16* __restrict__ W1T) {
    const int n = blockIdx.x;          // 0..127
    const int k = threadIdx.x;         // 0..255
    W1T[n * 256 + k] = (_Float16)W1[(size_t)k * 128 + n];
}

// ---------------------------------------------------------------- GEMM1 (f16 MFMA)
// B-stationary, ZERO barriers in K-loop; whole W1T in padded LDS; A streams
// global->reg->f16 nontemporal; M_rep=4 -> 32 MFMA per 8 ds_read_b128 +
// 8 global dwordx4 per k-step.
// Round-22: epilogue writes SLICED layout Hs[slice=nt][n][16] with dinv[n]
// PRE-FOLDED (same 2^-11 relative rounding as the old plain f16 store — the
// weight fold costs no extra precision, and deletes all dinv gathers from
// the aggregation kernel).
__global__ __launch_bounds__(256) void gemm1_mfma(const float* __restrict__ X,
                                                  const _Float16* __restrict__ W1T,
                                                  const float* __restrict__ dinv,
                                                  _Float16* __restrict__ Hs) {
    __shared__ _Float16 Bs[128][BSTR];   // 67.6 KB -> 2 blocks/CU

    const int tid  = threadIdx.x;
    const int wave = tid >> 6;
    const int lane = tid & 63;
    const int m16  = lane & 15;
    const int quad = lane >> 4;
    const int rowBase = blockIdx.x * 256 + wave * 64;

    // ---- preload whole W1T into LDS (16 x b128 per thread), once
#pragma unroll
    for (int i = 0; i < 16; ++i) {
        const int c  = tid + 256 * i;         // 4096 chunks of 16B
        const int n  = c >> 5;                // row (col of W1)
        const int kb = (c & 31) * 16;         // byte within row
        *(f16x8*)((char*)&Bs[n][0] + kb) = *(const f16x8*)((const char*)W1T + (size_t)c * 16);
    }
    __syncthreads();   // the only barrier in the kernel

    f32x4 acc[4][8] = {};
    f32x4 avA[8];

    auto loadA = [&](int k0) {
#pragma unroll
        for (int m = 0; m < 4; ++m) {
            int gr = rowBase + m * 16 + m16;
            gr = gr < N ? gr : N - 1;         // clamp (stores guarded)
            const f32x4* p = (const f32x4*)&X[(size_t)gr * 256 + k0 + quad * 8];
            avA[2 * m]     = __builtin_nontemporal_load(p);
            avA[2 * m + 1] = __builtin_nontemporal_load(p + 1);
        }
    };

    loadA(0);
    for (int k0 = 0; k0 < 256; k0 += 32) {
        f16x8 af[4];
#pragma unroll
        for (int m = 0; m < 4; ++m) {
            f16x8 h;
            h[0] = (_Float16)avA[2*m][0];   h[1] = (_Float16)avA[2*m][1];
            h[2] = (_Float16)avA[2*m][2];   h[3] = (_Float16)avA[2*m][3];
            h[4] = (_Float16)avA[2*m+1][0]; h[5] = (_Float16)avA[2*m+1][1];
            h[6] = (_Float16)avA[2*m+1][2]; h[7] = (_Float16)avA[2*m+1][3];
            af[m] = h;
        }
        if (k0 + 32 < 256) loadA(k0 + 32);    // prefetch next tile into regs
#pragma unroll
        for (int nt = 0; nt < 8; ++nt) {
            const f16x8 bf = *(const f16x8*)&Bs[nt * 16 + m16][k0 + quad * 8];
#pragma unroll
            for (int m = 0; m < 4; ++m)
                acc[m][nt] = __builtin_amdgcn_mfma_f32_16x16x32_f16(af[m], bf, acc[m][nt], 0, 0, 0);
        }
    }

    // ---- epilogue: C/D layout col=lane&15, row=quad*4+r (verified convention)
    float dv[4][4];
#pragma unroll
    for (int m = 0; m < 4; ++m)
#pragma unroll
        for (int r = 0; r < 4; ++r) {
            const int gm = rowBase + m * 16 + quad * 4 + r;
            dv[m][r] = (gm < N) ? dinv[gm] : 0.f;
        }
#pragma unroll
    for (int m = 0; m < 4; ++m)
#pragma unroll
        for (int nt = 0; nt < 8; ++nt)
#pragma unroll
            for (int r = 0; r < 4; ++r) {
                const int gm = rowBase + m * 16 + quad * 4 + r;
                if (gm < N)
                    Hs[(size_t)nt * N * 16 + (size_t)gm * 16 + m16] =
                        (_Float16)(acc[m][nt][r] * dv[m][r]);
            }
}

// ---------------------------------------------------------------- Sliced agg1 (+bias+ReLU)
// Round-22: round-21 counters (95us, VALU 29%, FETCH 200MB @2.2TB/s) showed
// the bound is L2-miss traffic on H gathers: 25.6MB H vs 4MB per-XCD L2.
// Aggregation+ReLU are per-feature -> slice 128 feats into 8x16; slice k
// runs entirely on XCD k (blockIdx&7 routing, proven by round-11 fill):
// per-XCD working set = 3.2MB slice < 4MB L2 -> gathers become L2 hits.
// Wave = 1 node: 4 edge-subgroups x 16 feats; edges pre-scaled by dinv[src]
// (folded in gemm1) so the loop is a pure masked sum of 32B gathers.
__global__ __launch_bounds__(512) void agg1s(const _Float16* __restrict__ Hs,
                                             const int* __restrict__ cnt,
                                             const int* __restrict__ rp,
                                             const int* __restrict__ colc,
                                             const float* __restrict__ dinv,
                                             const float* __restrict__ b1,
                                             float* __restrict__ Hr) {
    const int k  = blockIdx.x & 7;                      // slice -> XCD
    const int nw = (blockIdx.x >> 3) * 8 + (threadIdx.x >> 6);
    if (nw >= N) return;
    const int lane = threadIdx.x & 63;
    const int eg   = lane >> 4;      // edge subgroup 0..3
    const int f    = lane & 15;      // feature within slice
    const int n    = __builtin_amdgcn_readfirstlane(nw);
    const int c    = min(__builtin_amdgcn_readfirstlane(cnt[n]), CAP);
    const int rpn  = __builtin_amdgcn_readfirstlane(rp[n]);

    const _Float16* hb = Hs + (size_t)k * N * 16 + f;

    float a = 0.f;
    const int tot4 = (c + 1 + 3) & ~3;
    int s0[4]; float m0[4]; _Float16 v0[4];
#pragma unroll
    for (int t = 0; t < 4; ++t) {
        const int e   = eg + 4 * t;
        const int ecl = e < c ? e : (c > 0 ? c - 1 : 0);
        s0[t] = (e < c) ? colc[rpn + ecl] : n;
        m0[t] = (e <= c) ? 1.f : 0.f;
    }
#pragma unroll
    for (int t = 0; t < 4; ++t) v0[t] = hb[(size_t)s0[t] * 16];
    for (int j = 16; j < tot4; j += 16) {
        int s1[4]; float m1[4]; _Float16 v1[4];
#pragma unroll
        for (int t = 0; t < 4; ++t) {
            const int e   = eg + j + 4 * t;
            const int ecl = e < c ? e : (c > 0 ? c - 1 : 0);
            s1[t] = (e < c) ? colc[rpn + ecl] : n;
            m1[t] = (e <= c) ? 1.f : 0.f;
        }
#pragma unroll
        for (int t = 0; t < 4; ++t) v1[t] = hb[(size_t)s1[t] * 16];
#pragma unroll
        for (int t = 0; t < 4; ++t) {
            a = fmaf(m0[t], (float)v0[t], a);
            v0[t] = v1[t]; m0[t] = m1[t];
        }
    }
#pragma unroll
    for (int t = 0; t < 4; ++t) a = fmaf(m0[t], (float)v0[t], a);

    // reduce over the 4 edge subgroups (same f)
    a += __shfl_xor(a, 16);
    a += __shfl_xor(a, 32);

    const float h = fmaxf(fmaf(a, dinv[n], b1[k * 16 + f]), 0.f);
    if (eg == 0) Hr[((size_t)k * N + n) * 16 + f] = h;   // 16 lanes = 64B contiguous
}

// ---------------------------------------------------------------- GEMM2 (128 -> 8)
// Wave per node; sequential slice reads (no gather); the expensive 8-value
// 64-lane reduction now happens ONCE per node (round-21 did it per wave too,
// but now agg1s doesn't pay it 8x).
__global__ __launch_bounds__(256) void gemm2k(const float* __restrict__ Hr,
                                              const float* __restrict__ W2,
                                              float* __restrict__ Z) {
    const int nw   = (blockIdx.x * blockDim.x + threadIdx.x) >> 6;
    const int lane = threadIdx.x & 63;
    if (nw >= N) return;
    const int n  = __builtin_amdgcn_readfirstlane(nw);
    const int k  = lane >> 3;            // slice
    const int f2 = (lane & 7) * 2;       // feature pair within slice
    const float2 h2 = *(const float2*)&Hr[((size_t)k * N + n) * 16 + f2];
    const int row = k * 16 + f2;
    const float4 wa0 = *(const float4*)&W2[(size_t)row * 8];
    const float4 wa1 = *(const float4*)&W2[(size_t)row * 8 + 4];
    const float4 wb0 = *(const float4*)&W2[(size_t)(row + 1) * 8];
    const float4 wb1 = *(const float4*)&W2[(size_t)(row + 1) * 8 + 4];
    float p[8];
    p[0] = h2.x * wa0.x + h2.y * wb0.x;
    p[1] = h2.x * wa0.y + h2.y * wb0.y;
    p[2] = h2.x * wa0.z + h2.y * wb0.z;
    p[3] = h2.x * wa0.w + h2.y * wb0.w;
    p[4] = h2.x * wa1.x + h2.y * wb1.x;
    p[5] = h2.x * wa1.y + h2.y * wb1.y;
    p[6] = h2.x * wa1.z + h2.y * wb1.z;
    p[7] = h2.x * wa1.w + h2.y * wb1.w;
#pragma unroll
    for (int off = 32; off > 0; off >>= 1)
#pragma unroll
        for (int j = 0; j < 8; ++j) p[j] += __shfl_xor(p[j], off);
    if (lane == 0) {
        *(float4*)&Z[(size_t)n * 8]     = make_float4(p[0], p[1], p[2], p[3]);
        *(float4*)&Z[(size_t)n * 8 + 4] = make_float4(p[4], p[5], p[6], p[7]);
    }
}

// ---------------------------------------------------------------- Aggregation layer 2 (F=8)
// 8 lanes per node (lane=feat): 12.5K waves, Z-row read = one coalesced 32B
// request per octet, colc/dinv loads same-address broadcasts within octet.
__global__ __launch_bounds__(256) void agg2(const float* __restrict__ Z,
                                            const int* __restrict__ cnt,
                                            const int* __restrict__ rp,
                                            const int* __restrict__ colc,
                                            const float* __restrict__ dinv,
                                            const float* __restrict__ b2,
                                            float* __restrict__ ZA) {
    const int t = blockIdx.x * blockDim.x + threadIdx.x;
    const int n = t >> 3;              // node
    const int f = t & 7;               // feature
    if (n >= N) return;
    const int c   = min(cnt[n], CAP);
    const int rpn = rp[n];

    float acc = 0.f;
    float zv[4], wv[4];
#pragma unroll
    for (int tt = 0; tt < 4; ++tt) {
        const int s = (tt < c) ? colc[rpn + tt] : n;
        wv[tt] = (tt < c) ? dinv[s] : 0.0f;
        zv[tt] = Z[(size_t)s * 8 + f];
    }
    for (int j = 4; j + 4 <= c + 4; j += 4) {
        float zb[4], wb[4];
#pragma unroll
        for (int tt = 0; tt < 4; ++tt) {
            const int jt = j + tt;
            const int s  = (jt < c) ? colc[rpn + jt] : n;
            wb[tt] = (jt < c) ? dinv[s] : 0.0f;
            zb[tt] = Z[(size_t)s * 8 + f];
        }
#pragma unroll
        for (int tt = 0; tt < 4; ++tt) {
            acc = fmaf(wv[tt], zv[tt], acc);
            zv[tt] = zb[tt]; wv[tt] = wb[tt];
        }
    }
#pragma unroll
    for (int tt = 0; tt < 4; ++tt) acc = fmaf(wv[tt], zv[tt], acc);

    const float dn = dinv[n];
    const float zn = Z[(size_t)n * 8 + f];
    ZA[(size_t)n * 8 + f] = (acc + dn * zn) * dn + b2[f];
}

// ---------------------------------------------------------------- Edge scoring
__global__ __launch_bounds__(256) void score(const float* __restrict__ ZA,
                                             const int* __restrict__ pe,
                                             const int* __restrict__ ne,
                                             float* __restrict__ out) {
    const int e = blockIdx.x * blockDim.x + threadIdx.x;
    if (e >= ES) return;
    int a, b;
    if (e < EP) { a = pe[e];      b = pe[EP + e]; }
    else        { a = ne[e - EP]; b = ne[e];      }
    const float4 xa0 = *(const float4*)&ZA[(size_t)a * 8];
    const float4 xa1 = *(const float4*)&ZA[(size_t)a * 8 + 4];
    const float4 xb0 = *(const float4*)&ZA[(size_t)b * 8];
    const float4 xb1 = *(const float4*)&ZA[(size_t)b * 8 + 4];
    out[e] = xa0.x * xb0.x + xa0.y * xb0.y + xa0.z * xb0.z + xa0.w * xb0.w +
             xa1.x * xb1.x + xa1.y * xb1.y + xa1.z * xb1.z + xa1.w * xb1.w;
}

// ---------------------------------------------------------------- launch

extern "C" void kernel_launch(void* const* d_in, const int* in_sizes, int n_in,
                              void* d_out, int out_size, void* d_ws, size_t ws_size,
                              hipStream_t stream) {
    const float* x  = (const float*)d_in[0];
    const int*   ei = (const int*)d_in[1];   // [2, 1.6M] row-major
    const int*   pe = (const int*)d_in[2];   // [2, 200k]
    const int*   ne = (const int*)d_in[3];   // [2, 200k]
    const float* W1 = (const float*)d_in[4];
    const float* b1 = (const float*)d_in[5];
    const float* W2 = (const float*)d_in[6];
    const float* b2 = (const float*)d_in[7];
    float* out = (float*)d_out;

    char* ws = (char*)d_ws;
    size_t off = 0;
    auto carve = [&](size_t bytes) {
        char* p = ws + off;
        off += (bytes + 255) & ~(size_t)255;
        return p;
    };
    int*       gcnt = (int*)      carve((size_t)XG2 * sizeof(int));          // 512 B
    int*       cnt  = (int*)      carve((size_t)N * sizeof(int));            // 0.4 MB
    int*       rp   = (int*)      carve((size_t)N * sizeof(int));            // 0.4 MB
    float*     dinv = (float*)    carve((size_t)N * sizeof(float));          // 0.4 MB
    unsigned*  eb   = (unsigned*) carve((size_t)XG2 * SEGCAP * sizeof(unsigned)); // 7.0 MB
    int*       colc = (int*)      carve(((size_t)XG2 * SEGCAP + 64) * sizeof(int)); // 7.0 MB + pad
    _Float16*  Hs   = (_Float16*) carve((size_t)8 * N * 16 * sizeof(_Float16)); // 25.6 MB (sliced, dinv-folded)
    float*     Hr   = (float*)    carve((size_t)8 * N * 16 * sizeof(float));    // 51.2 MB (post-ReLU, f32)
    float*     Z    = (float*)    carve((size_t)N * 8 * sizeof(float));      // 3.2 MB
    float*     ZA   = (float*)    carve((size_t)N * 8 * sizeof(float));      // 3.2 MB
    _Float16*  W1T  = (_Float16*) carve((size_t)128 * 256 * sizeof(_Float16)); // 64 KB

    hipMemsetAsync(gcnt, 0, (size_t)XG2 * sizeof(int), stream);
    partition_edges<<<NPB, PBS, 0, stream>>>(ei, gcnt, eb);
    w1_transpose   <<<128, 256, 0, stream>>>(W1, W1T);
    fill_csr       <<<XG2, 1024, 0, stream>>>(eb, gcnt, cnt, rp, dinv, colc);
    gemm1_mfma     <<<(N + 255) / 256, 256, 0, stream>>>(x, W1T, dinv, Hs);
    agg1s          <<<8 * ((N + 7) / 8), 512, 0, stream>>>(Hs, cnt, rp, colc, dinv, b1, Hr);
    gemm2k         <<<((size_t)N * 64 + 255) / 256, 256, 0, stream>>>(Hr, W2, Z);
    agg2           <<<((size_t)N * 8 + 255) / 256, 256, 0, stream>>>(Z, cnt, rp, colc, dinv, b2, ZA);
    score          <<<(ES + 255) / 256, 256, 0, stream>>>(ZA, pe, ne, out);
}

// Round 11
// 437.220 us; speedup vs baseline: 1.1563x; 1.1563x over previous
//
#include <hip/hip_runtime.h>

constexpr int N   = 100000;   // nodes
constexpr int E   = 1600000;  // message edges
constexpr int EP  = 200000;   // pos scored edges
constexpr int ES  = 400000;   // total scored edges (pos+neg)
constexpr int CAP = 64;       // per-node fan-in clamp for lane-gather (Poisson(16): P(deg>64)~1e-18)
constexpr int XG2 = 128;      // radix groups (CSR counting-sort fill)
constexpr int DR2 = (N + XG2 - 1) / XG2;    // 782 nodes per group
constexpr int SEGCAP = 14336; // per-group segment capacity (E/128=12500 mean, +16 sigma)
constexpr int EPB = 8192;     // edges per partition block
constexpr int PBS = 1024;     // partition block size
constexpr int NPB = (E + EPB - 1) / EPB;    // 196 partition blocks
constexpr int BSTR = 264;     // gemm1 LDS B k-stride (f16): 264*2B=528B -> bank (4n+4q)%32, 2-way max

typedef _Float16 f16x8 __attribute__((ext_vector_type(8)));
typedef _Float16 f16x4 __attribute__((ext_vector_type(4)));
typedef _Float16 f16x2 __attribute__((ext_vector_type(2)));
typedef float    f32x4 __attribute__((ext_vector_type(4)));

// ---------------------------------------------------------------- Pass A: partition edges
// 196 blocks x 8192 edges, LDS histogram + ONE global atomic per group per
// block. 128 groups; pack = rel(10b)<<17 | src(17b).
__global__ __launch_bounds__(1024) void partition_edges(const int* __restrict__ ei,
                                                        int* __restrict__ gcnt,
                                                        unsigned* __restrict__ eb) {
    __shared__ int lh[XG2];   // block histogram
    __shared__ int rk[XG2];   // running rank counters (init = global base)
    const int tid = threadIdx.x;
    const int e0  = blockIdx.x * EPB;
    if (tid < XG2) lh[tid] = 0;
    __syncthreads();
#pragma unroll
    for (int i = 0; i < EPB; i += PBS) {
        const int e = e0 + i + tid;
        if (e < E) {
            const int d = ei[E + e];
            atomicAdd(&lh[d / DR2], 1);
        }
    }
    __syncthreads();
    if (tid < XG2) rk[tid] = atomicAdd(&gcnt[tid], lh[tid]);  // one hot atomic per group per block
    __syncthreads();
#pragma unroll
    for (int i = 0; i < EPB; i += PBS) {
        const int e = e0 + i + tid;
        if (e < E) {
            const int s   = ei[e];
            const int d   = ei[E + e];
            const int g   = d / DR2;
            const int rel = d - g * DR2;               // < 782 < 2^10
            const int p   = atomicAdd(&rk[g], 1);
            if (p < SEGCAP)
                eb[(size_t)g * SEGCAP + p] = ((unsigned)rel << 17) | (unsigned)s;
        }
    }
}

// ---------------------------------------------------------------- Pass B: CSR counting sort
// 4B scattered col stores cannot be L2-merged (rounds 16/18); one 1024-thread
// block per group finishes the sort in LDS, writes everything coalesced.
// Also emits dinv[n] = rsqrt(deg+1).
__global__ __launch_bounds__(1024) void fill_csr(const unsigned* __restrict__ eb,
                                                 const int* __restrict__ gcnt,
                                                 int* __restrict__ cnt,
                                                 int* __restrict__ rp,
                                                 float* __restrict__ dinv,
                                                 int* __restrict__ colc) {
    __shared__ int hcnt[1024];          // counts -> cursors (DR2=782 used)
    __shared__ int wsum[16];
    __shared__ unsigned stage[SEGCAP];  // 57.3 KB
    const int g   = blockIdx.x;
    const int tid = threadIdx.x;
    const int cg  = min(gcnt[g], SEGCAP);
    const unsigned* seg = eb + (size_t)g * SEGCAP;

    hcnt[tid] = 0;
    __syncthreads();
    for (int i = tid; i < cg; i += 1024)
        atomicAdd(&hcnt[seg[i] >> 17], 1);
    __syncthreads();

    // exclusive scan over 1024 counters (wave scan + wave-sum scan)
    const int c    = hcnt[tid];
    const int lane = tid & 63;
    const int wid  = tid >> 6;
    int incl = c;
#pragma unroll
    for (int off = 1; off < 64; off <<= 1) {
        const int v = __shfl_up(incl, off);
        if (lane >= off) incl += v;
    }
    if (lane == 63) wsum[wid] = incl;
    __syncthreads();
    if (tid < 16) {
        int v = wsum[tid];
#pragma unroll
        for (int off = 1; off < 16; off <<= 1) {
            const int u = __shfl_up(v, off);
            if (tid >= off) v += u;
        }
        wsum[tid] = v;   // inclusive wave sums
    }
    __syncthreads();
    const int excl = incl - c + (wid ? wsum[wid - 1] : 0);

    const int base = g * DR2;
    if (tid < DR2 && base + tid < N) {
        cnt [base + tid] = c;                      // full in-degree
        rp  [base + tid] = g * SEGCAP + excl;      // CSR row start
        dinv[base + tid] = rsqrtf((float)c + 1.0f);
    }
    __syncthreads();       // scan reads done before cursor overwrite
    hcnt[tid] = excl;
    __syncthreads();

    for (int i = tid; i < cg; i += 1024) {
        const unsigned pk = seg[i];
        const int p = atomicAdd(&hcnt[pk >> 17], 1);
        stage[p] = pk & 0x1FFFFu;
    }
    __syncthreads();
    for (int i = tid; i < cg; i += 1024)
        colc[(size_t)g * SEGCAP + i] = (int)stage[i];   // full-line streaming writes
}

// ---------------------------------------------------------------- W1 transpose prep
__global__ __launch_bounds__(256) void w1_transpose(const float* __restrict__ W1,
                                                    _Float16* __restrict__ W1T) {
    const int n = blockIdx.x;          // 0..127
    const int k = threadIdx.x;         // 0..255
    W1T[n * 256 + k] = (_Float16)W1[(size_t)k * 128 + n];
}

// ---------------------------------------------------------------- GEMM1 (f16 MFMA)
// B-stationary, ZERO barriers in K-loop; whole W1T in padded LDS; A streams
// global->reg->f16 nontemporal; M_rep=4 -> 32 MFMA per 8 ds_read_b128 +
// 8 global dwordx4 per k-step. Epilogue writes SLICED layout
// Hs[slice=nt][n][16] with dinv[n] pre-folded.
__global__ __launch_bounds__(256) void gemm1_mfma(const float* __restrict__ X,
                                                  const _Float16* __restrict__ W1T,
                                                  const float* __restrict__ dinv,
                                                  _Float16* __restrict__ Hs) {
    __shared__ _Float16 Bs[128][BSTR];   // 67.6 KB -> 2 blocks/CU

    const int tid  = threadIdx.x;
    const int wave = tid >> 6;
    const int lane = tid & 63;
    const int m16  = lane & 15;
    const int quad = lane >> 4;
    const int rowBase = blockIdx.x * 256 + wave * 64;

    // ---- preload whole W1T into LDS (16 x b128 per thread), once
#pragma unroll
    for (int i = 0; i < 16; ++i) {
        const int c  = tid + 256 * i;         // 4096 chunks of 16B
        const int n  = c >> 5;                // row (col of W1)
        const int kb = (c & 31) * 16;         // byte within row
        *(f16x8*)((char*)&Bs[n][0] + kb) = *(const f16x8*)((const char*)W1T + (size_t)c * 16);
    }
    __syncthreads();   // the only barrier in the kernel

    f32x4 acc[4][8] = {};
    f32x4 avA[8];

    auto loadA = [&](int k0) {
#pragma unroll
        for (int m = 0; m < 4; ++m) {
            int gr = rowBase + m * 16 + m16;
            gr = gr < N ? gr : N - 1;         // clamp (stores guarded)
            const f32x4* p = (const f32x4*)&X[(size_t)gr * 256 + k0 + quad * 8];
            avA[2 * m]     = __builtin_nontemporal_load(p);
            avA[2 * m + 1] = __builtin_nontemporal_load(p + 1);
        }
    };

    loadA(0);
    for (int k0 = 0; k0 < 256; k0 += 32) {
        f16x8 af[4];
#pragma unroll
        for (int m = 0; m < 4; ++m) {
            f16x8 h;
            h[0] = (_Float16)avA[2*m][0];   h[1] = (_Float16)avA[2*m][1];
            h[2] = (_Float16)avA[2*m][2];   h[3] = (_Float16)avA[2*m][3];
            h[4] = (_Float16)avA[2*m+1][0]; h[5] = (_Float16)avA[2*m+1][1];
            h[6] = (_Float16)avA[2*m+1][2]; h[7] = (_Float16)avA[2*m+1][3];
            af[m] = h;
        }
        if (k0 + 32 < 256) loadA(k0 + 32);    // prefetch next tile into regs
#pragma unroll
        for (int nt = 0; nt < 8; ++nt) {
            const f16x8 bf = *(const f16x8*)&Bs[nt * 16 + m16][k0 + quad * 8];
#pragma unroll
            for (int m = 0; m < 4; ++m)
                acc[m][nt] = __builtin_amdgcn_mfma_f32_16x16x32_f16(af[m], bf, acc[m][nt], 0, 0, 0);
        }
    }

    // ---- epilogue: C/D layout col=lane&15, row=quad*4+r (verified convention)
    float dv[4][4];
#pragma unroll
    for (int m = 0; m < 4; ++m)
#pragma unroll
        for (int r = 0; r < 4; ++r) {
            const int gm = rowBase + m * 16 + quad * 4 + r;
            dv[m][r] = (gm < N) ? dinv[gm] : 0.f;
        }
#pragma unroll
    for (int m = 0; m < 4; ++m)
#pragma unroll
        for (int nt = 0; nt < 8; ++nt)
#pragma unroll
            for (int r = 0; r < 4; ++r) {
                const int gm = rowBase + m * 16 + quad * 4 + r;
                if (gm < N)
                    Hs[(size_t)nt * N * 16 + (size_t)gm * 16 + m16] =
                        (_Float16)(acc[m][nt][r] * dv[m][r]);
            }
}

// ---------------------------------------------------------------- Sliced agg1 (+bias+ReLU)
// Round-23: round-22's agg1s proved slice-residency works (FETCH 200->55MB)
// but was wave-overhead bound (800K waves, 2B/lane loads, VALU 68%, 203us).
// Restructure: wave = 8 CONSECUTIVE nodes x 8 lanes (lane = f16x2 = 2 feats,
// 16 feats/node). Per step: 8 edges via ONE 256B gather instr (8x32B chunks)
// + near-contiguous colc subgroup loads. 100K waves (8x fewer); prologue per
// 8 nodes; NO cross-lane reduce (lane owns its 2 output feats). Slice k
// pinned to XCD k via blockIdx&7 as before.
__global__ __launch_bounds__(256) void agg1s(const _Float16* __restrict__ Hs,
                                             const int* __restrict__ cnt,
                                             const int* __restrict__ rp,
                                             const int* __restrict__ colc,
                                             const float* __restrict__ dinv,
                                             const float* __restrict__ b1,
                                             float* __restrict__ Hr) {
    const int k    = blockIdx.x & 7;             // slice -> XCD
    const int wave = threadIdx.x >> 6;
    const int lane = threadIdx.x & 63;
    const int j    = lane >> 3;                  // node subgroup 0..7
    const int fl   = lane & 7;                   // feature-pair lane
    const int n    = (blockIdx.x >> 3) * 32 + wave * 8 + j;   // N = 32*3125 exact
    const int c    = min(cnt[n], CAP);           // subgroup-uniform
    const int rj   = rp[n];
    const _Float16* hb = Hs + (size_t)k * N * 16 + fl * 2;

    float ax = 0.f, ay = 0.f;
    f16x2 va[4]; float ma[4];
    const int tot4 = (c + 1 + 3) & ~3;
#pragma unroll
    for (int t = 0; t < 4; ++t) {
        const int ec = t < c ? t : c;
        const int s  = (ec < c) ? colc[rj + ec] : n;
        ma[t] = (t <= c) ? 1.f : 0.f;
        va[t] = *(const f16x2*)&hb[(size_t)s * 16];
    }
    for (int j4 = 4; j4 < tot4; j4 += 4) {
        f16x2 vb[4]; float mb[4];
#pragma unroll
        for (int t = 0; t < 4; ++t) {
            const int e  = j4 + t;
            const int ec = e < c ? e : c;
            const int s  = (ec < c) ? colc[rj + ec] : n;
            mb[t] = (e <= c) ? 1.f : 0.f;
            vb[t] = *(const f16x2*)&hb[(size_t)s * 16];
        }
#pragma unroll
        for (int t = 0; t < 4; ++t) {
            ax = fmaf(ma[t], (float)va[t][0], ax);
            ay = fmaf(ma[t], (float)va[t][1], ay);
            va[t] = vb[t]; ma[t] = mb[t];
        }
    }
#pragma unroll
    for (int t = 0; t < 4; ++t) {
        ax = fmaf(ma[t], (float)va[t][0], ax);
        ay = fmaf(ma[t], (float)va[t][1], ay);
    }

    const float dn  = dinv[n];
    const float2 bb = *(const float2*)&b1[k * 16 + fl * 2];
    float2 o;
    o.x = fmaxf(fmaf(ax, dn, bb.x), 0.f);
    o.y = fmaxf(fmaf(ay, dn, bb.y), 0.f);
    *(float2*)&Hr[((size_t)k * N + n) * 16 + fl * 2] = o;   // 64B/node, 512B/wave contiguous
}

// ---------------------------------------------------------------- GEMM2 (128 -> 8)
// Wave per node; sequential slice reads (no gather); the expensive 8-value
// 64-lane reduction happens ONCE per node.
__global__ __launch_bounds__(256) void gemm2k(const float* __restrict__ Hr,
                                              const float* __restrict__ W2,
                                              float* __restrict__ Z) {
    const int nw   = (blockIdx.x * blockDim.x + threadIdx.x) >> 6;
    const int lane = threadIdx.x & 63;
    if (nw >= N) return;
    const int n  = __builtin_amdgcn_readfirstlane(nw);
    const int k  = lane >> 3;            // slice
    const int f2 = (lane & 7) * 2;       // feature pair within slice
    const float2 h2 = *(const float2*)&Hr[((size_t)k * N + n) * 16 + f2];
    const int row = k * 16 + f2;
    const float4 wa0 = *(const float4*)&W2[(size_t)row * 8];
    const float4 wa1 = *(const float4*)&W2[(size_t)row * 8 + 4];
    const float4 wb0 = *(const float4*)&W2[(size_t)(row + 1) * 8];
    const float4 wb1 = *(const float4*)&W2[(size_t)(row + 1) * 8 + 4];
    float p[8];
    p[0] = h2.x * wa0.x + h2.y * wb0.x;
    p[1] = h2.x * wa0.y + h2.y * wb0.y;
    p[2] = h2.x * wa0.z + h2.y * wb0.z;
    p[3] = h2.x * wa0.w + h2.y * wb0.w;
    p[4] = h2.x * wa1.x + h2.y * wb1.x;
    p[5] = h2.x * wa1.y + h2.y * wb1.y;
    p[6] = h2.x * wa1.z + h2.y * wb1.z;
    p[7] = h2.x * wa1.w + h2.y * wb1.w;
#pragma unroll
    for (int off = 32; off > 0; off >>= 1)
#pragma unroll
        for (int j = 0; j < 8; ++j) p[j] += __shfl_xor(p[j], off);
    if (lane == 0) {
        *(float4*)&Z[(size_t)n * 8]     = make_float4(p[0], p[1], p[2], p[3]);
        *(float4*)&Z[(size_t)n * 8 + 4] = make_float4(p[4], p[5], p[6], p[7]);
    }
}

// ---------------------------------------------------------------- Aggregation layer 2 (F=8)
// 8 lanes per node (lane=feat): 12.5K waves, Z-row read = one coalesced 32B
// request per octet, colc/dinv loads same-address broadcasts within octet.
__global__ __launch_bounds__(256) void agg2(const float* __restrict__ Z,
                                            const int* __restrict__ cnt,
                                            const int* __restrict__ rp,
                                            const int* __restrict__ colc,
                                            const float* __restrict__ dinv,
                                            const float* __restrict__ b2,
                                            float* __restrict__ ZA) {
    const int t = blockIdx.x * blockDim.x + threadIdx.x;
    const int n = t >> 3;              // node
    const int f = t & 7;               // feature
    if (n >= N) return;
    const int c   = min(cnt[n], CAP);
    const int rpn = rp[n];

    float acc = 0.f;
    float zv[4], wv[4];
#pragma unroll
    for (int tt = 0; tt < 4; ++tt) {
        const int s = (tt < c) ? colc[rpn + tt] : n;
        wv[tt] = (tt < c) ? dinv[s] : 0.0f;
        zv[tt] = Z[(size_t)s * 8 + f];
    }
    for (int j = 4; j + 4 <= c + 4; j += 4) {
        float zb[4], wb[4];
#pragma unroll
        for (int tt = 0; tt < 4; ++tt) {
            const int jt = j + tt;
            const int s  = (jt < c) ? colc[rpn + jt] : n;
            wb[tt] = (jt < c) ? dinv[s] : 0.0f;
            zb[tt] = Z[(size_t)s * 8 + f];
        }
#pragma unroll
        for (int tt = 0; tt < 4; ++tt) {
            acc = fmaf(wv[tt], zv[tt], acc);
            zv[tt] = zb[tt]; wv[tt] = wb[tt];
        }
    }
#pragma unroll
    for (int tt = 0; tt < 4; ++tt) acc = fmaf(wv[tt], zv[tt], acc);

    const float dn = dinv[n];
    const float zn = Z[(size_t)n * 8 + f];
    ZA[(size_t)n * 8 + f] = (acc + dn * zn) * dn + b2[f];
}

// ---------------------------------------------------------------- Edge scoring
__global__ __launch_bounds__(256) void score(const float* __restrict__ ZA,
                                             const int* __restrict__ pe,
                                             const int* __restrict__ ne,
                                             float* __restrict__ out) {
    const int e = blockIdx.x * blockDim.x + threadIdx.x;
    if (e >= ES) return;
    int a, b;
    if (e < EP) { a = pe[e];      b = pe[EP + e]; }
    else        { a = ne[e - EP]; b = ne[e];      }
    const float4 xa0 = *(const float4*)&ZA[(size_t)a * 8];
    const float4 xa1 = *(const float4*)&ZA[(size_t)a * 8 + 4];
    const float4 xb0 = *(const float4*)&ZA[(size_t)b * 8];
    const float4 xb1 = *(const float4*)&ZA[(size_t)b * 8 + 4];
    out[e] = xa0.x * xb0.x + xa0.y * xb0.y + xa0.z * xb0.z + xa0.w * xb0.w +
             xa1.x * xb1.x + xa1.y * xb1.y + xa1.z * xb1.z + xa1.w * xb1.w;
}

// ---------------------------------------------------------------- launch

extern "C" void kernel_launch(void* const* d_in, const int* in_sizes, int n_in,
                              void* d_out, int out_size, void* d_ws, size_t ws_size,
                              hipStream_t stream) {
    const float* x  = (const float*)d_in[0];
    const int*   ei = (const int*)d_in[1];   // [2, 1.6M] row-major
    const int*   pe = (const int*)d_in[2];   // [2, 200k]
    const int*   ne = (const int*)d_in[3];   // [2, 200k]
    const float* W1 = (const float*)d_in[4];
    const float* b1 = (const float*)d_in[5];
    const float* W2 = (const float*)d_in[6];
    const float* b2 = (const float*)d_in[7];
    float* out = (float*)d_out;

    char* ws = (char*)d_ws;
    size_t off = 0;
    auto carve = [&](size_t bytes) {
        char* p = ws + off;
        off += (bytes + 255) & ~(size_t)255;
        return p;
    };
    int*       gcnt = (int*)      carve((size_t)XG2 * sizeof(int));          // 512 B
    int*       cnt  = (int*)      carve((size_t)N * sizeof(int));            // 0.4 MB
    int*       rp   = (int*)      carve((size_t)N * sizeof(int));            // 0.4 MB
    float*     dinv = (float*)    carve((size_t)N * sizeof(float));          // 0.4 MB
    unsigned*  eb   = (unsigned*) carve((size_t)XG2 * SEGCAP * sizeof(unsigned)); // 7.0 MB
    int*       colc = (int*)      carve(((size_t)XG2 * SEGCAP + 64) * sizeof(int)); // 7.0 MB + pad
    _Float16*  Hs   = (_Float16*) carve((size_t)8 * N * 16 * sizeof(_Float16)); // 25.6 MB (sliced, dinv-folded)
    float*     Hr   = (float*)    carve((size_t)8 * N * 16 * sizeof(float));    // 51.2 MB (post-ReLU, f32)
    float*     Z    = (float*)    carve((size_t)N * 8 * sizeof(float));      // 3.2 MB
    float*     ZA   = (float*)    carve((size_t)N * 8 * sizeof(float));      // 3.2 MB
    _Float16*  W1T  = (_Float16*) carve((size_t)128 * 256 * sizeof(_Float16)); // 64 KB

    hipMemsetAsync(gcnt, 0, (size_t)XG2 * sizeof(int), stream);
    partition_edges<<<NPB, PBS, 0, stream>>>(ei, gcnt, eb);
    w1_transpose   <<<128, 256, 0, stream>>>(W1, W1T);
    fill_csr       <<<XG2, 1024, 0, stream>>>(eb, gcnt, cnt, rp, dinv, colc);
    gemm1_mfma     <<<(N + 255) / 256, 256, 0, stream>>>(x, W1T, dinv, Hs);
    agg1s          <<<8 * (N / 32), 256, 0, stream>>>(Hs, cnt, rp, colc, dinv, b1, Hr);
    gemm2k         <<<((size_t)N * 64 + 255) / 256, 256, 0, stream>>>(Hr, W2, Z);
    agg2           <<<((size_t)N * 8 + 255) / 256, 256, 0, stream>>>(Z, cnt, rp, colc, dinv, b2, ZA);
    score          <<<(ES + 255) / 256, 256, 0, stream>>>(ZA, pe, ne, out);
}

// Round 12
// 326.944 us; speedup vs baseline: 1.5463x; 1.3373x over previous
//
#include <hip/hip_runtime.h>

constexpr int N   = 100000;   // nodes
constexpr int E   = 1600000;  // message edges
constexpr int EP  = 200000;   // pos scored edges
constexpr int ES  = 400000;   // total scored edges (pos+neg)
constexpr int CAP = 64;       // per-node fan-in clamp for lane-gather (Poisson(16): P(deg>64)~1e-18)
constexpr int XG2 = 128;      // radix groups (CSR counting-sort fill)
constexpr int DR2 = (N + XG2 - 1) / XG2;    // 782 nodes per group
constexpr int SEGCAP = 14336; // per-group segment capacity (E/128=12500 mean, +16 sigma)
constexpr int EPB = 8192;     // edges per partition block
constexpr int PBS = 1024;     // partition block size
constexpr int NPB = (E + EPB - 1) / EPB;    // 196 partition blocks
constexpr int BSTR = 264;     // gemm1 LDS B k-stride (f16): 264*2B=528B -> bank (4n+4q)%32, 2-way max

typedef _Float16 f16x8 __attribute__((ext_vector_type(8)));
typedef _Float16 f16x4 __attribute__((ext_vector_type(4)));
typedef _Float16 f16x2 __attribute__((ext_vector_type(2)));
typedef float    f32x4 __attribute__((ext_vector_type(4)));

// ---------------------------------------------------------------- Pass A: partition edges
// 196 blocks x 8192 edges, LDS histogram + ONE global atomic per group per
// block. 128 groups; pack = rel(10b)<<17 | src(17b).
__global__ __launch_bounds__(1024) void partition_edges(const int* __restrict__ ei,
                                                        int* __restrict__ gcnt,
                                                        unsigned* __restrict__ eb) {
    __shared__ int lh[XG2];   // block histogram
    __shared__ int rk[XG2];   // running rank counters (init = global base)
    const int tid = threadIdx.x;
    const int e0  = blockIdx.x * EPB;
    if (tid < XG2) lh[tid] = 0;
    __syncthreads();
#pragma unroll
    for (int i = 0; i < EPB; i += PBS) {
        const int e = e0 + i + tid;
        if (e < E) {
            const int d = ei[E + e];
            atomicAdd(&lh[d / DR2], 1);
        }
    }
    __syncthreads();
    if (tid < XG2) rk[tid] = atomicAdd(&gcnt[tid], lh[tid]);  // one hot atomic per group per block
    __syncthreads();
#pragma unroll
    for (int i = 0; i < EPB; i += PBS) {
        const int e = e0 + i + tid;
        if (e < E) {
            const int s   = ei[e];
            const int d   = ei[E + e];
            const int g   = d / DR2;
            const int rel = d - g * DR2;               // < 782 < 2^10
            const int p   = atomicAdd(&rk[g], 1);
            if (p < SEGCAP)
                eb[(size_t)g * SEGCAP + p] = ((unsigned)rel << 17) | (unsigned)s;
        }
    }
}

// ---------------------------------------------------------------- Pass B: CSR counting sort
// 4B scattered col stores cannot be L2-merged (rounds 16/18); one 1024-thread
// block per group finishes the sort in LDS, writes everything coalesced.
// Also emits dinv[n] = rsqrt(deg+1).
__global__ __launch_bounds__(1024) void fill_csr(const unsigned* __restrict__ eb,
                                                 const int* __restrict__ gcnt,
                                                 int* __restrict__ cnt,
                                                 int* __restrict__ rp,
                                                 float* __restrict__ dinv,
                                                 int* __restrict__ colc) {
    __shared__ int hcnt[1024];          // counts -> cursors (DR2=782 used)
    __shared__ int wsum[16];
    __shared__ unsigned stage[SEGCAP];  // 57.3 KB
    const int g   = blockIdx.x;
    const int tid = threadIdx.x;
    const int cg  = min(gcnt[g], SEGCAP);
    const unsigned* seg = eb + (size_t)g * SEGCAP;

    hcnt[tid] = 0;
    __syncthreads();
    for (int i = tid; i < cg; i += 1024)
        atomicAdd(&hcnt[seg[i] >> 17], 1);
    __syncthreads();

    // exclusive scan over 1024 counters (wave scan + wave-sum scan)
    const int c    = hcnt[tid];
    const int lane = tid & 63;
    const int wid  = tid >> 6;
    int incl = c;
#pragma unroll
    for (int off = 1; off < 64; off <<= 1) {
        const int v = __shfl_up(incl, off);
        if (lane >= off) incl += v;
    }
    if (lane == 63) wsum[wid] = incl;
    __syncthreads();
    if (tid < 16) {
        int v = wsum[tid];
#pragma unroll
        for (int off = 1; off < 16; off <<= 1) {
            const int u = __shfl_up(v, off);
            if (tid >= off) v += u;
        }
        wsum[tid] = v;   // inclusive wave sums
    }
    __syncthreads();
    const int excl = incl - c + (wid ? wsum[wid - 1] : 0);

    const int base = g * DR2;
    if (tid < DR2 && base + tid < N) {
        cnt [base + tid] = c;                      // full in-degree
        rp  [base + tid] = g * SEGCAP + excl;      // CSR row start
        dinv[base + tid] = rsqrtf((float)c + 1.0f);
    }
    __syncthreads();       // scan reads done before cursor overwrite
    hcnt[tid] = excl;
    __syncthreads();

    for (int i = tid; i < cg; i += 1024) {
        const unsigned pk = seg[i];
        const int p = atomicAdd(&hcnt[pk >> 17], 1);
        stage[p] = pk & 0x1FFFFu;
    }
    __syncthreads();
    for (int i = tid; i < cg; i += 1024)
        colc[(size_t)g * SEGCAP + i] = (int)stage[i];   // full-line streaming writes
}

// ---------------------------------------------------------------- W1 transpose prep
__global__ __launch_bounds__(256) void w1_transpose(const float* __restrict__ W1,
                                                    _Float16* __restrict__ W1T) {
    const int n = blockIdx.x;          // 0..127
    const int k = threadIdx.x;         // 0..255
    W1T[n * 256 + k] = (_Float16)W1[(size_t)k * 128 + n];
}

// ---------------------------------------------------------------- GEMM1 (f16 MFMA)
// B-stationary, ZERO barriers in K-loop; whole W1T in padded LDS; A streams
// global->reg->f16 nontemporal; M_rep=4 -> 32 MFMA per 8 ds_read_b128 +
// 8 global dwordx4 per k-step.
// Round-24: back to PLAIN H[n][128] layout (slicing reverted — round-22/23
// proved slice-residency cuts FETCH 200->55MB but loses more to per-edge
// addressing overhead than it gains: 95 -> 203/129us). KEEP the dinv fold
// (H row pre-scaled by dinv[n]): it deleted all per-edge dinv gathers from
// agg1 and improved absmax 4.88e-4 -> 2.44e-4.
__global__ __launch_bounds__(256) void gemm1_mfma(const float* __restrict__ X,
                                                  const _Float16* __restrict__ W1T,
                                                  const float* __restrict__ dinv,
                                                  _Float16* __restrict__ H) {
    __shared__ _Float16 Bs[128][BSTR];   // 67.6 KB -> 2 blocks/CU

    const int tid  = threadIdx.x;
    const int wave = tid >> 6;
    const int lane = tid & 63;
    const int m16  = lane & 15;
    const int quad = lane >> 4;
    const int rowBase = blockIdx.x * 256 + wave * 64;

    // ---- preload whole W1T into LDS (16 x b128 per thread), once
#pragma unroll
    for (int i = 0; i < 16; ++i) {
        const int c  = tid + 256 * i;         // 4096 chunks of 16B
        const int n  = c >> 5;                // row (col of W1)
        const int kb = (c & 31) * 16;         // byte within row
        *(f16x8*)((char*)&Bs[n][0] + kb) = *(const f16x8*)((const char*)W1T + (size_t)c * 16);
    }
    __syncthreads();   // the only barrier in the kernel

    f32x4 acc[4][8] = {};
    f32x4 avA[8];

    auto loadA = [&](int k0) {
#pragma unroll
        for (int m = 0; m < 4; ++m) {
            int gr = rowBase + m * 16 + m16;
            gr = gr < N ? gr : N - 1;         // clamp (stores guarded)
            const f32x4* p = (const f32x4*)&X[(size_t)gr * 256 + k0 + quad * 8];
            avA[2 * m]     = __builtin_nontemporal_load(p);
            avA[2 * m + 1] = __builtin_nontemporal_load(p + 1);
        }
    };

    loadA(0);
    for (int k0 = 0; k0 < 256; k0 += 32) {
        f16x8 af[4];
#pragma unroll
        for (int m = 0; m < 4; ++m) {
            f16x8 h;
            h[0] = (_Float16)avA[2*m][0];   h[1] = (_Float16)avA[2*m][1];
            h[2] = (_Float16)avA[2*m][2];   h[3] = (_Float16)avA[2*m][3];
            h[4] = (_Float16)avA[2*m+1][0]; h[5] = (_Float16)avA[2*m+1][1];
            h[6] = (_Float16)avA[2*m+1][2]; h[7] = (_Float16)avA[2*m+1][3];
            af[m] = h;
        }
        if (k0 + 32 < 256) loadA(k0 + 32);    // prefetch next tile into regs
#pragma unroll
        for (int nt = 0; nt < 8; ++nt) {
            const f16x8 bf = *(const f16x8*)&Bs[nt * 16 + m16][k0 + quad * 8];
#pragma unroll
            for (int m = 0; m < 4; ++m)
                acc[m][nt] = __builtin_amdgcn_mfma_f32_16x16x32_f16(af[m], bf, acc[m][nt], 0, 0, 0);
        }
    }

    // ---- epilogue: C/D layout col=lane&15, row=quad*4+r (verified convention)
    float dv[4][4];
#pragma unroll
    for (int m = 0; m < 4; ++m)
#pragma unroll
        for (int r = 0; r < 4; ++r) {
            const int gm = rowBase + m * 16 + quad * 4 + r;
            dv[m][r] = (gm < N) ? dinv[gm] : 0.f;
        }
#pragma unroll
    for (int m = 0; m < 4; ++m)
#pragma unroll
        for (int nt = 0; nt < 8; ++nt)
#pragma unroll
            for (int r = 0; r < 4; ++r) {
                const int gm = rowBase + m * 16 + quad * 4 + r;
                if (gm < N)
                    H[(size_t)gm * 128 + nt * 16 + m16] =
                        (_Float16)(acc[m][nt][r] * dv[m][r]);
            }
}

// ---------------------------------------------------------------- Fused agg1 + gemm2
// Round-24: round-9 structure restored (95us, ~96% of its 2.2TB/s-fabric
// floor for 200MB of gather misses) + dinv-fold: the edge loop is now a pure
// masked sum of pre-scaled H rows — no dinv loads at all. Wave per node;
// lane owns feats [2l,2l+1]; n/c/rpn in SGPRs (readfirstlane) -> colc loads
// scalar; depth-8 register pipeline.
__global__ __launch_bounds__(256) void agg1_gemm2(const _Float16* __restrict__ H,
                                                  const int* __restrict__ cnt,
                                                  const int* __restrict__ rp,
                                                  const int* __restrict__ colc,
                                                  const float* __restrict__ dinv,
                                                  const float* __restrict__ b1,
                                                  const float* __restrict__ W2,
                                                  float* __restrict__ Z) {
    const int nw   = (blockIdx.x * blockDim.x + threadIdx.x) >> 6;
    const int lane = threadIdx.x & 63;
    if (nw >= N) return;
    const int n   = __builtin_amdgcn_readfirstlane(nw);
    const int c   = min(__builtin_amdgcn_readfirstlane(cnt[n]), CAP);
    const int rpn = __builtin_amdgcn_readfirstlane(rp[n]);
    const float dn = dinv[n];

    const _Float16* hbase = H + lane * 2;

    // hoist epilogue operands above the edge loop (overlap their latency)
    const float2 b   = *(const float2*)&b1[lane * 2];
    const float4 wa0 = *(const float4*)&W2[(size_t)(lane * 2) * 8];
    const float4 wa1 = *(const float4*)&W2[(size_t)(lane * 2) * 8 + 4];
    const float4 wb0 = *(const float4*)&W2[(size_t)(lane * 2 + 1) * 8];
    const float4 wb1 = *(const float4*)&W2[(size_t)(lane * 2 + 1) * 8 + 4];

    // edge e in [0, c]: src = e<c ? colc[rpn+e] : n (self-loop). H rows are
    // pre-scaled by dinv[src], so weight is just the tail mask.
    f16x2 va[8]; float wa[8];
#pragma unroll
    for (int t = 0; t < 8; ++t) {
        const int ec = t < c ? t : c;              // uniform clamp
        const int s  = (ec < c) ? colc[rpn + ec] : n;
        wa[t] = (t <= c) ? 1.f : 0.f;
        va[t] = *(const f16x2*)&hbase[(size_t)s * 128];
    }
    float ax = 0.f, ay = 0.f;
    const int tot8 = (c + 1 + 7) & ~7;
    for (int j = 8; j < tot8; j += 8) {
        f16x2 vb[8]; float wb[8];
#pragma unroll
        for (int t = 0; t < 8; ++t) {
            const int e  = j + t;
            const int ec = e < c ? e : c;
            const int s  = (ec < c) ? colc[rpn + ec] : n;
            wb[t] = (e <= c) ? 1.f : 0.f;
            vb[t] = *(const f16x2*)&hbase[(size_t)s * 128];
        }
#pragma unroll
        for (int t = 0; t < 8; ++t) {
            ax = fmaf(wa[t], (float)va[t][0], ax);
            ay = fmaf(wa[t], (float)va[t][1], ay);
            va[t] = vb[t]; wa[t] = wb[t];
        }
    }
#pragma unroll
    for (int t = 0; t < 8; ++t) {
        ax = fmaf(wa[t], (float)va[t][0], ax);
        ay = fmaf(wa[t], (float)va[t][1], ay);
    }

    const float hr0 = fmaxf(fmaf(ax, dn, b.x), 0.f);
    const float hr1 = fmaxf(fmaf(ay, dn, b.y), 0.f);

    float p[8];
    p[0] = hr0 * wa0.x + hr1 * wb0.x;
    p[1] = hr0 * wa0.y + hr1 * wb0.y;
    p[2] = hr0 * wa0.z + hr1 * wb0.z;
    p[3] = hr0 * wa0.w + hr1 * wb0.w;
    p[4] = hr0 * wa1.x + hr1 * wb1.x;
    p[5] = hr0 * wa1.y + hr1 * wb1.y;
    p[6] = hr0 * wa1.z + hr1 * wb1.z;
    p[7] = hr0 * wa1.w + hr1 * wb1.w;
#pragma unroll
    for (int off = 32; off > 0; off >>= 1)
#pragma unroll
        for (int j = 0; j < 8; ++j) p[j] += __shfl_xor(p[j], off);
    if (lane == 0) {
        *(float4*)&Z[(size_t)n * 8]     = make_float4(p[0], p[1], p[2], p[3]);
        *(float4*)&Z[(size_t)n * 8 + 4] = make_float4(p[4], p[5], p[6], p[7]);
    }
}

// ---------------------------------------------------------------- Aggregation layer 2 (F=8)
// 8 lanes per node (lane=feat): 12.5K waves, Z-row read = one coalesced 32B
// request per octet, colc/dinv loads same-address broadcasts within octet.
__global__ __launch_bounds__(256) void agg2(const float* __restrict__ Z,
                                            const int* __restrict__ cnt,
                                            const int* __restrict__ rp,
                                            const int* __restrict__ colc,
                                            const float* __restrict__ dinv,
                                            const float* __restrict__ b2,
                                            float* __restrict__ ZA) {
    const int t = blockIdx.x * blockDim.x + threadIdx.x;
    const int n = t >> 3;              // node
    const int f = t & 7;               // feature
    if (n >= N) return;
    const int c   = min(cnt[n], CAP);
    const int rpn = rp[n];

    float acc = 0.f;
    float zv[4], wv[4];
#pragma unroll
    for (int tt = 0; tt < 4; ++tt) {
        const int s = (tt < c) ? colc[rpn + tt] : n;
        wv[tt] = (tt < c) ? dinv[s] : 0.0f;
        zv[tt] = Z[(size_t)s * 8 + f];
    }
    for (int j = 4; j + 4 <= c + 4; j += 4) {
        float zb[4], wb[4];
#pragma unroll
        for (int tt = 0; tt < 4; ++tt) {
            const int jt = j + tt;
            const int s  = (jt < c) ? colc[rpn + jt] : n;
            wb[tt] = (jt < c) ? dinv[s] : 0.0f;
            zb[tt] = Z[(size_t)s * 8 + f];
        }
#pragma unroll
        for (int tt = 0; tt < 4; ++tt) {
            acc = fmaf(wv[tt], zv[tt], acc);
            zv[tt] = zb[tt]; wv[tt] = wb[tt];
        }
    }
#pragma unroll
    for (int tt = 0; tt < 4; ++tt) acc = fmaf(wv[tt], zv[tt], acc);

    const float dn = dinv[n];
    const float zn = Z[(size_t)n * 8 + f];
    ZA[(size_t)n * 8 + f] = (acc + dn * zn) * dn + b2[f];
}

// ---------------------------------------------------------------- Edge scoring
__global__ __launch_bounds__(256) void score(const float* __restrict__ ZA,
                                             const int* __restrict__ pe,
                                             const int* __restrict__ ne,
                                             float* __restrict__ out) {
    const int e = blockIdx.x * blockDim.x + threadIdx.x;
    if (e >= ES) return;
    int a, b;
    if (e < EP) { a = pe[e];      b = pe[EP + e]; }
    else        { a = ne[e - EP]; b = ne[e];      }
    const float4 xa0 = *(const float4*)&ZA[(size_t)a * 8];
    const float4 xa1 = *(const float4*)&ZA[(size_t)a * 8 + 4];
    const float4 xb0 = *(const float4*)&ZA[(size_t)b * 8];
    const float4 xb1 = *(const float4*)&ZA[(size_t)b * 8 + 4];
    out[e] = xa0.x * xb0.x + xa0.y * xb0.y + xa0.z * xb0.z + xa0.w * xb0.w +
             xa1.x * xb1.x + xa1.y * xb1.y + xa1.z * xb1.z + xa1.w * xb1.w;
}

// ---------------------------------------------------------------- launch

extern "C" void kernel_launch(void* const* d_in, const int* in_sizes, int n_in,
                              void* d_out, int out_size, void* d_ws, size_t ws_size,
                              hipStream_t stream) {
    const float* x  = (const float*)d_in[0];
    const int*   ei = (const int*)d_in[1];   // [2, 1.6M] row-major
    const int*   pe = (const int*)d_in[2];   // [2, 200k]
    const int*   ne = (const int*)d_in[3];   // [2, 200k]
    const float* W1 = (const float*)d_in[4];
    const float* b1 = (const float*)d_in[5];
    const float* W2 = (const float*)d_in[6];
    const float* b2 = (const float*)d_in[7];
    float* out = (float*)d_out;

    char* ws = (char*)d_ws;
    size_t off = 0;
    auto carve = [&](size_t bytes) {
        char* p = ws + off;
        off += (bytes + 255) & ~(size_t)255;
        return p;
    };
    int*       gcnt = (int*)      carve((size_t)XG2 * sizeof(int));          // 512 B
    int*       cnt  = (int*)      carve((size_t)N * sizeof(int));            // 0.4 MB
    int*       rp   = (int*)      carve((size_t)N * sizeof(int));            // 0.4 MB
    float*     dinv = (float*)    carve((size_t)N * sizeof(float));          // 0.4 MB
    unsigned*  eb   = (unsigned*) carve((size_t)XG2 * SEGCAP * sizeof(unsigned)); // 7.0 MB
    int*       colc = (int*)      carve(((size_t)XG2 * SEGCAP + 64) * sizeof(int)); // 7.0 MB + pad
    _Float16*  H    = (_Float16*) carve((size_t)N * 128 * sizeof(_Float16)); // 25.6 MB (dinv-folded)
    float*     Z    = (float*)    carve((size_t)N * 8 * sizeof(float));      // 3.2 MB
    float*     ZA   = (float*)    carve((size_t)N * 8 * sizeof(float));      // 3.2 MB
    _Float16*  W1T  = (_Float16*) carve((size_t)128 * 256 * sizeof(_Float16)); // 64 KB

    hipMemsetAsync(gcnt, 0, (size_t)XG2 * sizeof(int), stream);
    partition_edges<<<NPB, PBS, 0, stream>>>(ei, gcnt, eb);
    w1_transpose   <<<128, 256, 0, stream>>>(W1, W1T);
    fill_csr       <<<XG2, 1024, 0, stream>>>(eb, gcnt, cnt, rp, dinv, colc);
    gemm1_mfma     <<<(N + 255) / 256, 256, 0, stream>>>(x, W1T, dinv, H);
    agg1_gemm2     <<<((size_t)N * 64 + 255) / 256, 256, 0, stream>>>(H, cnt, rp, colc, dinv, b1, W2, Z);
    agg2           <<<((size_t)N * 8 + 255) / 256, 256, 0, stream>>>(Z, cnt, rp, colc, dinv, b2, ZA);
    score          <<<(ES + 255) / 256, 256, 0, stream>>>(ZA, pe, ne, out);
}